// Round 10
// baseline (225.492 us; speedup 1.0000x reference)
//
#include <hip/hip_runtime.h>
#include <hip/hip_bf16.h>

// Problem constants
#define H 1024
#define NHEAD 16
#define HDIM 64
#define SEQ 2048
#define BATCH 2
#define M_TOT (BATCH * SEQ) // 4096 tokens
#define NQKV 3072           // fused QKV output cols

typedef __attribute__((ext_vector_type(8))) short bf16x8;  // 8 bf16 = 4 VGPRs (MFMA A/B frag)
typedef __attribute__((ext_vector_type(4))) float f32x4;   // 16x16 MFMA C/D frag
typedef __attribute__((ext_vector_type(16))) float f32x16; // 32x32 MFMA C/D frag

// (1/sqrt(HDIM)) * log2(e), folded into Q at the QKV-GEMM epilogue
#define C2_SCALE 0.18033688f

__device__ __forceinline__ unsigned short f2bf(float f) {
  union { float f; unsigned int u; } a;
  a.f = f;
  unsigned int u = a.u;
  return (unsigned short)((u + 0x7fffu + ((u >> 16) & 1u)) >> 16); // RNE
}

// packed f32x2 -> bf16x2 (v_cvt_pk_bf16_f32), low short = first arg
__device__ __forceinline__ unsigned int pkbf(float a, float b) {
  union { __hip_bfloat162 h; unsigned int u; } cv;
  cv.h = __float22bfloat162_rn(float2{a, b});
  return cv.u;
}

__device__ __forceinline__ float fast_exp2(float x) {
#if defined(__has_builtin) && __has_builtin(__builtin_amdgcn_exp2f)
  return __builtin_amdgcn_exp2f(x);
#else
  return exp2f(x);
#endif
}

// async global->LDS, 16B per lane. LDS dest is wave-uniform base + lane*16.
typedef const __attribute__((address_space(1))) void* gas1_t;
typedef __attribute__((address_space(3))) void* las3_t;
__device__ __forceinline__ void gload16(const void* g, void* l) {
  __builtin_amdgcn_global_load_lds((gas1_t)(unsigned long long)g,
                                   (las3_t)(unsigned int)(unsigned long long)l,
                                   16, 0, 0);
}

// ---------------------------------------------------------------------------
// Kernel 1 (fused): LayerNorm rows (blocks 0..4095) + weight bf16 cast
// (blocks 4096..8191).
// ---------------------------------------------------------------------------
__global__ __launch_bounds__(256) void ln_cast_kernel(const float* __restrict__ x,
                                                      const float* __restrict__ gamma,
                                                      const float* __restrict__ beta,
                                                      unsigned short* __restrict__ xn,
                                                      const float* __restrict__ w0,
                                                      const float* __restrict__ w1,
                                                      const float* __restrict__ w2,
                                                      const float* __restrict__ w3,
                                                      unsigned short* __restrict__ wdst) {
  const int t = threadIdx.x;
  if (blockIdx.x >= M_TOT) {
    const int cb = blockIdx.x - M_TOT;   // 0..4095
    const int y = cb >> 10;              // matrix index 0..3
    const float* s = (y == 0) ? w0 : (y == 1) ? w1 : (y == 2) ? w2 : w3;
    const int i = (cb & 1023) * 256 + t; // float4 index within matrix
    const float4 v = ((const float4*)s)[i];
    ushort4 o;
    o.x = f2bf(v.x);
    o.y = f2bf(v.y);
    o.z = f2bf(v.z);
    o.w = f2bf(v.w);
    ((ushort4*)(wdst + (size_t)y * H * H))[i] = o;
    return;
  }
  const int row = blockIdx.x;
  const float* xr = x + (size_t)row * H;
  float4 v = ((const float4*)xr)[t];
  float s = v.x + v.y + v.z + v.w;
  float s2 = v.x * v.x + v.y * v.y + v.z * v.z + v.w * v.w;
#pragma unroll
  for (int o = 32; o; o >>= 1) {
    s += __shfl_xor(s, o, 64);
    s2 += __shfl_xor(s2, o, 64);
  }
  __shared__ float red[8];
  const int wave = t >> 6;
  if ((t & 63) == 0) {
    red[wave] = s;
    red[wave + 4] = s2;
  }
  __syncthreads();
  const float ts = red[0] + red[1] + red[2] + red[3];
  const float ts2 = red[4] + red[5] + red[6] + red[7];
  const float mu = ts * (1.0f / (float)H);
  const float var = ts2 * (1.0f / (float)H) - mu * mu;
  const float rstd = rsqrtf(var + 1e-5f);
  const float4 g = ((const float4*)gamma)[t];
  const float4 b = ((const float4*)beta)[t];
  ushort4 o;
  o.x = f2bf((v.x - mu) * rstd * g.x + b.x);
  o.y = f2bf((v.y - mu) * rstd * g.y + b.y);
  o.z = f2bf((v.z - mu) * rstd * g.z + b.z);
  o.w = f2bf((v.w - mu) * rstd * g.w + b.w);
  ((ushort4*)(xn + (size_t)row * H))[t] = o;
}

// ---------------------------------------------------------------------------
// 128x128x(BK=32) bf16 MFMA GEMM (16x16x32, 32 KB LDS, double-buffered,
// one barrier per K-iter, 4 blocks/CU), XCD-aware 1-D grid (unchanged).
// ---------------------------------------------------------------------------
template <int EPI, int NPX>
__global__ __launch_bounds__(256, 4) void gemm128(const unsigned short* __restrict__ A,
                                                  const unsigned short* __restrict__ W,
                                                  unsigned short* __restrict__ qk,
                                                  unsigned short* __restrict__ vt,
                                                  const float* __restrict__ bo,
                                                  const float* __restrict__ x,
                                                  float* __restrict__ out) {
  const int id = blockIdx.x;
  const int xcd = id & 7;
  const int r = id >> 3;
  const int nb = xcd * NPX + (r % NPX);
  const int mb = r / NPX;
  const int m0 = mb * 128;
  const int n0 = nb * 128;
  const int tid = threadIdx.x;
  const int wave = tid >> 6;
  const int lane = tid & 63;
  const int l16 = lane & 15;
  const int quad = lane >> 4;
  const int wx = wave & 1, wy = wave >> 1;

  __shared__ __align__(16) unsigned short As[2][128 * 32];
  __shared__ __align__(16) unsigned short Bs[2][128 * 32];

  const int sub = lane >> 2;       // row within 16-row group
  const int kcol = (lane & 3) * 8; // 4 lanes cover 32 cols
  const unsigned short* ag = A + (size_t)(m0 + wave * 32 + sub) * H + kcol;
  const unsigned short* bg = W + (size_t)(n0 + wave * 32 + sub) * H + kcol;
  const int lofs = wave * 32 * 32;

  f32x4 acc[4][4] = {};

  gload16(ag, &As[0][lofs]);
  gload16(ag + 16 * H, &As[0][lofs + 16 * 32]);
  gload16(bg, &Bs[0][lofs]);
  gload16(bg + 16 * H, &Bs[0][lofs + 16 * 32]);

  for (int it = 0; it < H / 32; it++) {
    const int bi = it & 1;
    __syncthreads(); // drains buf[bi] loads (issued a full iter ago)
    if (it + 1 < H / 32) {
      const int k1 = (it + 1) * 32;
      gload16(ag + k1, &As[bi ^ 1][lofs]);
      gload16(ag + k1 + 16 * H, &As[bi ^ 1][lofs + 16 * 32]);
      gload16(bg + k1, &Bs[bi ^ 1][lofs]);
      gload16(bg + k1 + 16 * H, &Bs[bi ^ 1][lofs + 16 * 32]);
    }
    bf16x8 af[4], bf[4];
#pragma unroll
    for (int t = 0; t < 4; t++) {
      af[t] = *(const bf16x8*)&As[bi][(wy * 64 + t * 16 + l16) * 32 + quad * 8];
      bf[t] = *(const bf16x8*)&Bs[bi][(wx * 64 + t * 16 + l16) * 32 + quad * 8];
    }
#pragma unroll
    for (int i = 0; i < 4; i++)
#pragma unroll
      for (int j = 0; j < 4; j++)
        acc[i][j] = __builtin_amdgcn_mfma_f32_16x16x32_bf16(af[i], bf[j], acc[i][j], 0, 0, 0);
  }

  if (EPI == 0) {
#pragma unroll
    for (int j = 0; j < 4; j++) {
      const int cb = n0 + wx * 64 + j * 16; // wave-uniform tile col base
      if (cb < 2048) {
        const float qs = (cb < 1024) ? C2_SCALE : 1.0f;
#pragma unroll
        for (int i = 0; i < 4; i++) {
          const int row = m0 + wy * 64 + i * 16 + quad * 4;
#pragma unroll
          for (int r2 = 0; r2 < 4; r2++)
            qk[(size_t)(row + r2) * 2048 + cb + l16] = f2bf(acc[i][j][r2] * qs);
        }
      } else {
        const int n = cb + l16 - 2048; // h*64+d
#pragma unroll
        for (int i = 0; i < 4; i++) {
          const int row0 = m0 + wy * 64 + i * 16 + quad * 4;
          const int b = row0 >> 11;
          const int s = row0 & 2047;
          ushort4 p;
          p.x = f2bf(acc[i][j][0]);
          p.y = f2bf(acc[i][j][1]);
          p.z = f2bf(acc[i][j][2]);
          p.w = f2bf(acc[i][j][3]);
          *(ushort4*)&vt[((size_t)b * 1024 + n) * SEQ + s] = p;
        }
      }
    }
  } else {
#pragma unroll
    for (int j = 0; j < 4; j++) {
      const int col = n0 + wx * 64 + j * 16 + l16;
      const float bv = bo[col];
#pragma unroll
      for (int i = 0; i < 4; i++) {
        const int row = m0 + wy * 64 + i * 16 + quad * 4;
#pragma unroll
        for (int r2 = 0; r2 < 4; r2++) {
          const size_t idx = (size_t)(row + r2) * H + col;
          out[idx] = acc[i][j][r2] + bv + x[idx];
        }
      }
    }
  }
}

// ---------------------------------------------------------------------------
// Flash attention v5: 32x32x16 MFMA, NO P LDS round-trip.
// Wave = 32 q-rows (lane l32 = qrow, hh = lane>>5). S^T = K·Q^T arrives with
// lane owning one q-row (col=l32); C/D->B-operand relayout for PV is done by
// a lane<->lane^32 exchange (8 shfl_xor(32)/iter) instead of LDS.
// LDS 32 KB (Kt+Vt double-buffered only). Fixed-max softmax (p=exp2(s)).
// 32x32 C/D layout: col=lane&31, row=(r&3)+8*(r>>2)+4*hh (m74/m101-verified).
// A/B operand: [m|n = lane&31][k = hh*8+j].
// Grid 512 blocks, XCD-supertiled (4 (b,h) combos per XCD).
// ---------------------------------------------------------------------------
__global__ __launch_bounds__(256, 2) void attn_kernel(const unsigned short* __restrict__ qk,
                                                      const unsigned short* __restrict__ vt,
                                                      unsigned short* __restrict__ O) {
  const int id = blockIdx.x; // 512 blocks
  const int xcd = id & 7;
  const int slot = id >> 3;      // 0..63
  const int qt = slot & 15;      // q-tile within (b,h)
  const int g = slot >> 4;       // 0..3
  const int combo = xcd * 4 + g; // 0..31
  const int h = combo & 15;
  const int b = combo >> 4;
  const int tid = threadIdx.x;
  const int wave = tid >> 6;
  const int lane = tid & 63;
  const int l32 = lane & 31;
  const int hh = lane >> 5;
  const int l8 = l32 & 7;

  __shared__ __align__(16) unsigned short Kt[2][64 * 64]; // [s][d], row-swizzled
  __shared__ __align__(16) unsigned short Vt[2][64 * 64]; // [d][s], row-swizzled

  const unsigned short* Qbase = qk + (size_t)b * SEQ * 2048 + h * 64;
  const unsigned short* Kbase = qk + (size_t)b * SEQ * 2048 + 1024 + h * 64;
  const unsigned short* Vbase = vt + ((size_t)b * 1024 + h * 64) * SEQ;

  // staging geometry: one gload16 covers 8 rows x 64 shorts (1 KB); XOR swizzle
  // in the GLOBAL address: LDS[row][pg] holds global 16B-group pg ^ (row&7)
  const int rIn = lane >> 3;
  const int gsw = (lane & 7) ^ rIn;
  const int ch0 = 2 * wave;

  // Q fragments (B-operand, held in regs): bq[ks] = Q[qrow][ks*16 + hh*8 + j]
  const int qrow = qt * 128 + wave * 32 + l32;
  bf16x8 bq[4];
#pragma unroll
  for (int ks = 0; ks < 4; ks++)
    bq[ks] = *(const bf16x8*)(Qbase + (size_t)qrow * 2048 + ks * 16 + hh * 8);

  float lacc[2] = {0.0f, 0.0f}; // partial denominator (this lane's 32 kcols/iter)
  f32x16 o_acc[2] = {};         // O^T: col=l32=qrow, d = dt*32+4*hh+(r&3)+8*(r>>2)

  // prologue: stage tile 0 into buffer 0
#pragma unroll
  for (int c = 0; c < 2; c++) {
    const int ch = ch0 + c;
    const int row = ch * 8 + rIn;
    gload16(Kbase + (size_t)row * 2048 + gsw * 8, &Kt[0][ch * 512]);
    gload16(Vbase + (size_t)row * SEQ + gsw * 8, &Vt[0][ch * 512]);
  }

#pragma unroll 2
  for (int it = 0; it < SEQ / 64; it++) {
    const int bi = it & 1;
    __syncthreads(); // waits cur-buffer loads (vmcnt) + prev iter readers done
    if (it + 1 < SEQ / 64) {
#pragma unroll
      for (int c = 0; c < 2; c++) {
        const int ch = ch0 + c;
        const int row = ch * 8 + rIn;
        gload16(Kbase + (size_t)((it + 1) * 64 + row) * 2048 + gsw * 8,
                &Kt[bi ^ 1][ch * 512]);
        gload16(Vbase + (size_t)row * SEQ + (it + 1) * 64 + gsw * 8,
                &Vt[bi ^ 1][ch * 512]);
      }
    }

    // S^T = K (A) @ Q^T (B): mt = kcol-tile; lane col = qrow
    f32x16 sa[2] = {};
#pragma unroll
    for (int ks = 0; ks < 4; ks++) {
#pragma unroll
      for (int mt = 0; mt < 2; mt++) {
        const bf16x8 kf = *(const bf16x8*)&Kt[bi][(mt * 32 + l32) * 64 +
                                                  (((ks * 2 + hh) ^ l8) * 8)];
        sa[mt] = __builtin_amdgcn_mfma_f32_32x32x16_bf16(kf, bq[ks], sa[mt], 0, 0, 0);
      }
    }

    // fixed-max softmax: p = exp2(s); pack pairs (consecutive kcols)
    unsigned int pk[2][8];
#pragma unroll
    for (int mt = 0; mt < 2; mt++) {
      float p[16];
#pragma unroll
      for (int r2 = 0; r2 < 16; r2++) p[r2] = fast_exp2(sa[mt][r2]);
      float ls = 0.0f;
#pragma unroll
      for (int r2 = 0; r2 < 16; r2++) ls += p[r2];
      lacc[mt] += ls;
#pragma unroll
      for (int q = 0; q < 8; q++) pk[mt][q] = pkbf(p[2 * q], p[2 * q + 1]);
    }

    // lane<->lane^32 exchange: I need partner's pk[mt][4*half + 2*hh + c];
    // symmetric send of pk[mt][4*half + 2*(1-hh) + c] delivers exactly that.
    unsigned int rcv[2][2][2];
#pragma unroll
    for (int mt = 0; mt < 2; mt++)
#pragma unroll
      for (int half = 0; half < 2; half++)
#pragma unroll
        for (int c = 0; c < 2; c++) {
          const unsigned int snd =
              hh ? pk[mt][4 * half + c] : pk[mt][4 * half + 2 + c];
          rcv[mt][half][c] = (unsigned int)__shfl_xor((int)snd, 32, 64);
        }

    // O^T += V^T (A) @ P^T (B): assemble P B-frag from own + received halves
#pragma unroll
    for (int ks = 0; ks < 4; ks++) {
      const int mt = ks >> 1;
      const int half = ks & 1;
      const unsigned int o0 = pk[mt][4 * half + 2 * hh + 0];
      const unsigned int o1 = pk[mt][4 * half + 2 * hh + 1];
      const unsigned int r0 = rcv[mt][half][0];
      const unsigned int r1 = rcv[mt][half][1];
      union { unsigned int w[4]; bf16x8 v; } pb;
      pb.w[0] = hh ? r0 : o0; // j0j1  (rows from hh'=0 holder)
      pb.w[1] = hh ? r1 : o1; // j2j3
      pb.w[2] = hh ? o0 : r0; // j4j5  (rows from hh'=1 holder)
      pb.w[3] = hh ? o1 : r1; // j6j7
#pragma unroll
      for (int dt = 0; dt < 2; dt++) {
        const bf16x8 vf = *(const bf16x8*)&Vt[bi][(dt * 32 + l32) * 64 +
                                                  (((ks * 2 + hh) ^ l8) * 8)];
        o_acc[dt] = __builtin_amdgcn_mfma_f32_32x32x16_bf16(vf, pb.v, o_acc[dt], 0, 0, 0);
      }
    }
  }

  // epilogue: l = own 32 kcols + partner's 32 (lane^32 shares qrow)
  float l_i = lacc[0] + lacc[1];
  l_i += __shfl_xor(l_i, 32, 64);
  const float inv = 1.0f / l_i;
  unsigned short* orow = O + ((size_t)(b * SEQ + qrow)) * H + h * 64;
#pragma unroll
  for (int dt = 0; dt < 2; dt++) {
#pragma unroll
    for (int s2 = 0; s2 < 4; s2++) { // r = 4*s2 + {0..3} -> d = dt*32+4hh+8*s2+{0..3}
      uint2 d;
      d.x = pkbf(o_acc[dt][4 * s2 + 0] * inv, o_acc[dt][4 * s2 + 1] * inv);
      d.y = pkbf(o_acc[dt][4 * s2 + 2] * inv, o_acc[dt][4 * s2 + 3] * inv);
      *(uint2*)&orow[dt * 32 + 4 * hh + 8 * s2] = d;
    }
  }
}

// ---------------------------------------------------------------------------
extern "C" void kernel_launch(void* const* d_in, const int* in_sizes, int n_in,
                              void* d_out, int out_size, void* d_ws, size_t ws_size,
                              hipStream_t stream) {
  const float* x = (const float*)d_in[0];
  const float* Wq = (const float*)d_in[1];
  const float* Wk = (const float*)d_in[2];
  const float* Wv = (const float*)d_in[3];
  const float* Wo = (const float*)d_in[4];
  const float* bo = (const float*)d_in[5];
  const float* gamma = (const float*)d_in[6];
  const float* beta = (const float*)d_in[7];
  float* out = (float*)d_out;

  unsigned short* ws = (unsigned short*)d_ws;
  unsigned short* xn = ws;                              // 4096*1024
  unsigned short* wcat = xn + (size_t)M_TOT * H;        // 4*1024*1024 (Wq,Wk,Wv,Wo)
  unsigned short* wob = wcat + (size_t)3 * H * H;
  unsigned short* qkb = wcat + (size_t)4 * H * H;       // 4096*2048 (Q | K)
  unsigned short* vtb = qkb + (size_t)M_TOT * 2048;     // 2*1024*2048 (V^T)
  unsigned short* atb = vtb + (size_t)BATCH * H * SEQ;  // 4096*1024

  ln_cast_kernel<<<M_TOT + 4096, 256, 0, stream>>>(x, gamma, beta, xn, Wq, Wk, Wv, Wo,
                                                   wcat);
  gemm128<0, 3><<<(M_TOT / 128) * (NQKV / 128), 256, 0, stream>>>(
      xn, wcat, qkb, vtb, nullptr, nullptr, nullptr);
  attn_kernel<<<(SEQ / 128) * NHEAD * BATCH, 256, 0, stream>>>(qkb, vtb, atb);
  gemm128<1, 1><<<(M_TOT / 128) * (H / 128), 256, 0, stream>>>(
      atb, wob, nullptr, nullptr, bo, x, out);
}